// Round 3
// baseline (511.185 us; speedup 1.0000x reference)
//
#include <hip/hip_runtime.h>

#define NPTS   32768
#define NCODES 8192
#define DIM    256

#define DECAYF 0.99f
#define ONE_MINUS_DECAYF ((float)(1.0 - 0.99))
#define EPSF   1e-5f
#define KEPSF  ((float)(8192.0 * 1e-5))
#define MARGIN 0.05f

// workspace byte offsets
#define WS_PART  0                                     // fp64 [8192] loss partials
#define WS_A     (WS_PART + NPTS / 4 * 8)              // fp32 [NPTS]
#define WS_EN    (WS_A + NPTS * 4)                     // fp32 [NCODES]
#define WS_CNT   (WS_EN + NCODES * 4)                  // int  [NCODES]
#define WS_S     (WS_CNT + NCODES * 4)                 // fp32 [NCODES] smoothed
#define WS_IDX   (WS_S + NCODES * 4)                   // int  [NPTS]
#define WS_OFFS  (WS_IDX + NPTS * 4)                   // int  [NCODES]
#define WS_CUR   (WS_OFFS + NCODES * 4)                // int  [NCODES]
#define WS_PLIST (WS_CUR + NCODES * 4)                 // int  [NPTS]
#define WS_EMBT  (WS_PLIST + NPTS * 4)                 // (unused, kept for layout)
#define WS_GMIN  (WS_EMBT + (size_t)DIM * NCODES * 4)  // fp32 [NPTS][512]     64 MB
#define WS_AH    (WS_GMIN + (size_t)NPTS * 512 * 4)    // bf16 [NPTS][256]     16 MB
#define WS_BH    (WS_AH + (size_t)NPTS * DIM * 2)      // bf16 [NCODES][256]    4 MB

typedef __attribute__((ext_vector_type(8))) short short8;
typedef __attribute__((ext_vector_type(4))) float f32x4;

__device__ inline void gl_lds16(const void* g, void* l) {
    __builtin_amdgcn_global_load_lds(
        (const __attribute__((address_space(1))) void*)g,
        (__attribute__((address_space(3))) void*)l, 16, 0, 0);
}

__device__ inline unsigned short f2bf(float f) {  // RNE float->bf16
    unsigned u = __float_as_uint(f);
    return (unsigned short)((u + 0x7FFFu + ((u >> 16) & 1u)) >> 16);
}
__device__ inline unsigned f2ord(float f) {       // monotone float->uint
    unsigned u = __float_as_uint(f);
    return (u & 0x80000000u) ? ~u : (u | 0x80000000u);
}

// ---------------------------------------------------------------------------
__global__ __launch_bounds__(256) void k_prep0(int* __restrict__ cnt) {
    int i = blockIdx.x * blockDim.x + threadIdx.x;
    if (i < NCODES) cnt[i] = 0;
}

// ---------------------------------------------------------------------------
__global__ __launch_bounds__(256) void k_rownorm(const float* __restrict__ x,
                                                 float* __restrict__ outn,
                                                 int nrows) {
    int w = (blockIdx.x * blockDim.x + threadIdx.x) >> 6;
    int lane = threadIdx.x & 63;
    if (w >= nrows) return;
    const float4 v = *(const float4*)(x + (size_t)w * DIM + 4 * lane);
    float q0 = v.x * v.x, q1 = v.y * v.y, q2 = v.z * v.z, q3 = v.w * v.w;
    double s = (double)q0 + (double)q1 + (double)q2 + (double)q3;
    #pragma unroll
    for (int off = 32; off > 0; off >>= 1) s += __shfl_down(s, off);
    if (lane == 0) outn[w] = (float)s;
}

// ---------------------------------------------------------------------------
// elementwise fp32 -> bf16-hi
__global__ __launch_bounds__(256) void k_split(const float* __restrict__ x,
                                               unsigned short* __restrict__ dst,
                                               int nelem) {
    int i = blockIdx.x * blockDim.x + threadIdx.x;
    int stride = gridDim.x * blockDim.x;
    for (int j = i; j < nelem; j += stride)
        dst[j] = f2bf(x[j]);
}

// ---------------------------------------------------------------------------
// Phase 1: bf16-hi MFMA GEMM, 256x256 tile, 8-phase schedule (T2+T3+T4+T5),
// PERSISTENT over 8 point-tiles per block (continuous 32-step pipeline).
// Operands SWAPPED vs reference: M = codes (MFMA A), N = points (MFMA B);
// gmin groups are LINEAR: group g holds codes [g*16, g*16+16).
//
// Per step s = it*4 + kt (buffer parity = kt&1, identical for every tile):
//  ph1 (mh0,nh0): ds_read af0(8)+bf0(4); stage A1[s+1] -> other buf
//  ph2 (mh0,nh1): ds_read bf1(4);        stage B1[s+1] -> other buf
//  ph3 (mh1,nh0): ds_read af1(8);        stage A0[s+2] -> THIS buf (dead rows)
//  ph4 (mh1,nh1): stage B0[s+2] -> THIS buf (dead rows); vmcnt(4); barrier
// A (codes) is tile-invariant: staging columns depend only on (s+k)&3.
// B pointers shift by one tile when (s+k) crosses a tile boundary (kt>=2).
// vmcnt(4) at each step end leaves exactly {A0,B0}[s+2] outstanding, so every
// region lands >= 1 full K-tile before first read -- including across tile
// boundaries (epilogue between tiles overlaps the in-flight prefetch; it uses
// a separate 16KB LDS region and raw lgkmcnt(0)+s_barrier, never vmcnt(0)).
// Last tile: next-tile B stages skipped (OOB guard); ledger => vmcnt(0) at
// (it==7,kt==2), nothing at (it==7,kt==3).

template<int MH>
__device__ __forceinline__ void dsr_a(const unsigned short* LB, int wr, int l15,
                                      int l7, int quad, short8 (&af)[4][2]) {
#pragma unroll
    for (int m4 = 0; m4 < 4; ++m4) {
        const int r = wr * 128 + (MH * 4 + m4) * 16 + l15;
#pragma unroll
        for (int kk = 0; kk < 2; ++kk)
            af[m4][kk] = *(const short8*)&LB[(r * 8 + ((kk * 4 + quad) ^ l7)) * 8];
    }
}
template<int NH>
__device__ __forceinline__ void dsr_b(const unsigned short* LB, int wc, int l15,
                                      int l7, int quad, short8 (&bf)[2][2]) {
#pragma unroll
    for (int n2 = 0; n2 < 2; ++n2) {
        const int r = wc * 64 + (NH * 2 + n2) * 16 + l15;
#pragma unroll
        for (int kk = 0; kk < 2; ++kk)
            bf[n2][kk] = *(const short8*)&LB[16384 + (r * 8 + ((kk * 4 + quad) ^ l7)) * 8];
    }
}
template<int MH, int NH>
__device__ __forceinline__ void mma8(const short8 (&af)[4][2], const short8 (&bf)[2][2],
                                     f32x4 (&acc)[8][4]) {
#pragma unroll
    for (int m4 = 0; m4 < 4; ++m4)
#pragma unroll
        for (int n2 = 0; n2 < 2; ++n2)
#pragma unroll
            for (int kk = 0; kk < 2; ++kk)
                acc[MH * 4 + m4][NH * 2 + n2] = __builtin_amdgcn_mfma_f32_16x16x32_bf16(
                    af[m4][kk], bf[n2][kk], acc[MH * 4 + m4][NH * 2 + n2], 0, 0, 0);
}

__global__ __launch_bounds__(512, 2) void k_gemm_argmin(
    const unsigned short* __restrict__ Ah,    // points [NPTS][256] bf16 bits
    const unsigned short* __restrict__ Bh,    // codes  [NCODES][256] bf16 bits
    const float* __restrict__ en,
    float* __restrict__ gmin) {               // [NPTS][512]
    // 128 KB dbuf (2 x (A 32K | B 32K)) + 16 KB epilogue scratch = 144 KB
    __shared__ __align__(16) unsigned short LDS[65536 + 8192];

    const int t = threadIdx.x;
    const int w = t >> 6, l = t & 63;
    const int quad = l >> 4, l15 = l & 15, l7 = l & 7;
    const int wr = w >> 2, wc = w & 3;

    // XCD-bijective swizzle (512 % 8 == 0): 64 consecutive lids per XCD;
    // 16 blocks sharing a code-tile land on one XCD -> L2 A-reuse.
    const int lid = (blockIdx.x & 7) * 64 + (blockIdx.x >> 3);
    const int cb = lid >> 4;                  // 32 code tiles (cb-major)
    const int pbg = lid & 15;                 // 16 point-tile groups (8 tiles each)
    const int cBase = cb * 256;

    // staging swizzle: element (row, kc) stored at 16B-slot (row*8 + (kc^(row&7)))
    // via pre-swizzled global source + linear LDS dest.
    const int lrs0 = t >> 3;                       // [0,64)
    const int xg = (t & 7) ^ (lrs0 & 7);
    const int rA0s0 = lrs0;                        // A0 rows {0-63}
    const int rA0s1 = 128 + lrs0;                  //          {128-191}
    const int rB0s0 = (lrs0 & 31) | ((lrs0 >> 5) << 6);  // B0 rows {0-31,64-95}
    const int rB0s1 = 128 + rB0s0;                 //          {128-159,192-223}

    const unsigned short* gA0s0 = Bh + (size_t)(cBase + rA0s0) * DIM + xg * 8;
    const unsigned short* gA0s1 = Bh + (size_t)(cBase + rA0s1) * DIM + xg * 8;
    const unsigned short* gBs0 = Ah + (size_t)(pbg * 8 * 256 + rB0s0) * DIM + xg * 8;
    const unsigned short* gBs1 = Ah + (size_t)(pbg * 8 * 256 + rB0s1) * DIM + xg * 8;

    // wave-uniform LDS dest bases (short offsets; row stride = 64 shorts)
    const int dA0s0 = (w * 8) * 64;
    const int dA0s1 = (128 + w * 8) * 64;
    const int dB0s0 = (((w & 3) * 8) | ((w >> 2) << 6)) * 64;
    const int dB0s1 = dB0s0 + 128 * 64;

#define STG_A0(CO, BUFS) do { \
        gl_lds16(gA0s0 + (CO) * 64, &LDS[(BUFS) + dA0s0]); \
        gl_lds16(gA0s1 + (CO) * 64, &LDS[(BUFS) + dA0s1]); } while (0)
#define STG_A1(CO, BUFS) do { \
        gl_lds16(gA0s0 + 64 * DIM + (CO) * 64, &LDS[(BUFS) + dA0s0 + 64 * 64]); \
        gl_lds16(gA0s1 + 64 * DIM + (CO) * 64, &LDS[(BUFS) + dA0s1 + 64 * 64]); } while (0)
#define STG_B0(P0, P1, CO, BUFS) do { \
        gl_lds16((P0) + (CO) * 64, &LDS[(BUFS) + 16384 + dB0s0]); \
        gl_lds16((P1) + (CO) * 64, &LDS[(BUFS) + 16384 + dB0s1]); } while (0)
#define STG_B1(P0, P1, CO, BUFS) do { \
        gl_lds16((P0) + 32 * DIM + (CO) * 64, &LDS[(BUFS) + 16384 + dB0s0 + 32 * 64]); \
        gl_lds16((P1) + 32 * DIM + (CO) * 64, &LDS[(BUFS) + 16384 + dB0s1 + 32 * 64]); } while (0)

    f32x4 acc[8][4];
#pragma unroll
    for (int i = 0; i < 8; ++i)
#pragma unroll
        for (int j = 0; j < 4; ++j) acc[i][j] = (f32x4){0.f, 0.f, 0.f, 0.f};

    // prologue: s=0 full -> buf0 (oldest 8 loads); s=1 {A0,B0} -> buf1
    STG_A0(0, 0); STG_B0(gBs0, gBs1, 0, 0); STG_A1(0, 0); STG_B1(gBs0, gBs1, 0, 0);
    STG_A0(1, 32768); STG_B0(gBs0, gBs1, 1, 32768);
    asm volatile("s_waitcnt vmcnt(4)");
    __builtin_amdgcn_sched_barrier(0);
    __builtin_amdgcn_s_barrier();

    short8 af[4][2], bf0[2][2], bf1[2][2];
#pragma unroll 1
    for (int it = 0; it < 8; ++it) {
        const unsigned short* bt0 = gBs0 + (size_t)it * (256 * DIM);
        const unsigned short* bt1 = gBs1 + (size_t)it * (256 * DIM);
        const unsigned short* bn0 = bt0 + 256 * DIM;
        const unsigned short* bn1 = bt1 + 256 * DIM;
        const bool more = (it < 7);
#pragma unroll
        for (int kt = 0; kt < 4; ++kt) {
            const int cbufS = (kt & 1) << 15;
            const int obufS = cbufS ^ 32768;
            const unsigned short* LB = &LDS[cbufS];
            const int co1 = (kt + 1) & 3, co2 = (kt + 2) & 3;
            // ---- phase 1 (mh0,nh0)
            dsr_a<0>(LB, wr, l15, l7, quad, af);
            dsr_b<0>(LB, wc, l15, l7, quad, bf0);
            if (kt < 3 || more) STG_A1(co1, obufS);
            __builtin_amdgcn_s_barrier();
            asm volatile("s_waitcnt lgkmcnt(0)");
            __builtin_amdgcn_sched_barrier(0);
            __builtin_amdgcn_s_setprio(1);
            mma8<0, 0>(af, bf0, acc);
            __builtin_amdgcn_s_setprio(0);
            __builtin_amdgcn_s_barrier();
            // ---- phase 2 (mh0,nh1)
            dsr_b<1>(LB, wc, l15, l7, quad, bf1);
            if (kt < 3) { STG_B1(bt0, bt1, co1, obufS); }
            else if (more) { STG_B1(bn0, bn1, co1, obufS); }
            __builtin_amdgcn_s_barrier();
            asm volatile("s_waitcnt lgkmcnt(0)");
            __builtin_amdgcn_sched_barrier(0);
            __builtin_amdgcn_s_setprio(1);
            mma8<0, 1>(af, bf1, acc);
            __builtin_amdgcn_s_setprio(0);
            __builtin_amdgcn_s_barrier();
            // ---- phase 3 (mh1,nh0)
            dsr_a<1>(LB, wr, l15, l7, quad, af);
            if (kt < 2 || more) STG_A0(co2, cbufS);
            __builtin_amdgcn_s_barrier();
            asm volatile("s_waitcnt lgkmcnt(0)");
            __builtin_amdgcn_sched_barrier(0);
            __builtin_amdgcn_s_setprio(1);
            mma8<1, 0>(af, bf0, acc);
            __builtin_amdgcn_s_setprio(0);
            __builtin_amdgcn_s_barrier();
            // ---- phase 4 (mh1,nh1)
            if (kt < 2) { STG_B0(bt0, bt1, co2, cbufS); }
            else if (more) { STG_B0(bn0, bn1, co2, cbufS); }
            __builtin_amdgcn_s_barrier();
            __builtin_amdgcn_s_setprio(1);
            mma8<1, 1>(af, bf1, acc);
            __builtin_amdgcn_s_setprio(0);
            if (kt < 2 || more) {
                asm volatile("s_waitcnt vmcnt(4)");
                __builtin_amdgcn_sched_barrier(0);
            } else if (kt == 2) {  // it==7: B0[s+2] skipped -> drain all
                asm volatile("s_waitcnt vmcnt(0)");
                __builtin_amdgcn_sched_barrier(0);
            }
            __builtin_amdgcn_s_barrier();
        }

        // ---- per-tile epilogue (separate LDS region; in-flight prefetch for
        // the next tile keeps flying -- no vmcnt here).
        float* outl = (float*)&LDS[65536];  // [16][256] fp32 = 16 KB
        const int pBase = (pbg * 8 + it) * 256;
#pragma unroll
        for (int m = 0; m < 8; ++m) {
            const float4 en4 = *(const float4*)&en[cBase + wr * 128 + m * 16 + quad * 4];
#pragma unroll
            for (int n = 0; n < 4; ++n) {
                f32x4 a = acc[m][n];
                float d0 = fmaf(-2.f, a[0], en4.x);
                float d1 = fmaf(-2.f, a[1], en4.y);
                float d2 = fmaf(-2.f, a[2], en4.z);
                float d3 = fmaf(-2.f, a[3], en4.w);
                float dm = fminf(fminf(d0, d1), fminf(d2, d3));
                dm = fminf(dm, __shfl_xor(dm, 16));
                dm = fminf(dm, __shfl_xor(dm, 32));
                if (quad == 0)
                    outl[(wr * 8 + m) * 256 + wc * 64 + n * 16 + l15] = dm;
            }
        }
        asm volatile("s_waitcnt lgkmcnt(0)");
        __builtin_amdgcn_sched_barrier(0);
        __builtin_amdgcn_s_barrier();
        {   // coalesced gmin write: tile covers gmin[pBase..+255][cb*16..+15]
            const int pt = t >> 1, h = t & 1;
#pragma unroll
            for (int q2 = 0; q2 < 2; ++q2) {
                const int g0 = (h * 2 + q2) * 4;
                float4 v;
                v.x = outl[(g0 + 0) * 256 + pt];
                v.y = outl[(g0 + 1) * 256 + pt];
                v.z = outl[(g0 + 2) * 256 + pt];
                v.w = outl[(g0 + 3) * 256 + pt];
                *(float4*)&gmin[(size_t)(pBase + pt) * 512 + cb * 16 + g0] = v;
            }
        }
        // reset accumulator for the next tile
#pragma unroll
        for (int i = 0; i < 8; ++i)
#pragma unroll
            for (int j = 0; j < 4; ++j) acc[i][j] = (f32x4){0.f, 0.f, 0.f, 0.f};
    }
#undef STG_A0
#undef STG_A1
#undef STG_B0
#undef STG_B1
}

// ---------------------------------------------------------------------------
// Phase 2: one wave per point. Approx global min over 512 group minima;
// rescore flagged groups exactly in fp32, reading emb ROWS cooperatively.
// Groups are LINEAR: group gid = codes [gid*16, gid*16+16).
__global__ __launch_bounds__(256) void k_phase2(
    const float* __restrict__ z, const float* __restrict__ emb,
    const float* __restrict__ A, const float* __restrict__ en,
    const float* __restrict__ gmin,
    int* __restrict__ widx, float* __restrict__ out1,
    int* __restrict__ cnt) {
    int wpt = (blockIdx.x << 2) + (threadIdx.x >> 6);  // point id
    int l = threadIdx.x & 63;

    const float* gp = gmin + (size_t)wpt * 512;
    float loc[8];
    #pragma unroll
    for (int i = 0; i < 8; ++i) loc[i] = gp[i * 64 + l];
    float m8 = loc[0];
    #pragma unroll
    for (int i = 1; i < 8; ++i) m8 = fminf(m8, loc[i]);
    #pragma unroll
    for (int off = 1; off < 64; off <<= 1) m8 = fminf(m8, __shfl_xor(m8, off));
    const float thresh = m8 + MARGIN;

    const float4 z4 = *(const float4*)(z + (size_t)wpt * DIM + 4 * l);
    const float Azn = A[wpt];
    unsigned long long best = ~0ull;
    #pragma unroll 1
    for (int i = 0; i < 8; ++i) {
        unsigned long long mask = __ballot(loc[i] <= thresh);
        while (mask) {
            int s = __ffsll((long long)mask) - 1;
            mask &= mask - 1;
            int cbase = (i * 64 + s) << 4;   // linear groups
            #pragma unroll 4
            for (int k = 0; k < 16; ++k) {
                int c = cbase + k;
                const float4 ev = *(const float4*)(emb + (size_t)c * DIM + 4 * l);
                float p = fmaf(z4.x, ev.x,
                          fmaf(z4.y, ev.y,
                          fmaf(z4.z, ev.z, z4.w * ev.w)));
                #pragma unroll
                for (int off = 1; off < 64; off <<= 1) p += __shfl_xor(p, off);
                float dist = (Azn - 2.0f * p) + en[c];
                unsigned long long pk =
                    ((unsigned long long)f2ord(dist) << 32) | (unsigned)c;
                best = pk < best ? pk : best;
            }
        }
    }
    if (l == 0) {
        int idx = (int)(unsigned)best;
        widx[wpt] = idx;
        out1[wpt] = (float)idx;
        atomicAdd(cnt + idx, 1);
    }
}

// ---------------------------------------------------------------------------
// single block: exclusive prefix of cnt -> offs (+cursor copy);
// out4 = ecs*0.99 + cnt*0.01; n = sum(out4); smoothed -> s_out.
__global__ __launch_bounds__(256) void k_scan(const int* __restrict__ cnt,
                                              const float* __restrict__ ecs,
                                              int* __restrict__ offs,
                                              int* __restrict__ cursor,
                                              float* __restrict__ out4,
                                              float* __restrict__ s_out) {
    __shared__ int ps[256];
    __shared__ double rd[256];
    __shared__ float nsh;
    int t = threadIdx.x;
    int base = t * 32;
    int loc[32];
    int s = 0;
    double nl = 0.0;
    #pragma unroll
    for (int i = 0; i < 32; ++i) {
        int c = cnt[base + i];
        loc[i] = c;
        s += c;
        float f = ecs[base + i] * DECAYF + (float)c * ONE_MINUS_DECAYF;
        out4[base + i] = f;
        nl += (double)f;
    }
    ps[t] = s;
    rd[t] = nl;
    __syncthreads();
    for (int off = 1; off < 256; off <<= 1) {
        int v = (t >= off) ? ps[t - off] : 0;
        __syncthreads();
        ps[t] += v;
        __syncthreads();
    }
    for (int off = 128; off > 0; off >>= 1) {
        if (t < off) rd[t] += rd[t + off];
        __syncthreads();
    }
    if (t == 0) nsh = (float)rd[0];
    __syncthreads();
    int run = (t == 0) ? 0 : ps[t - 1];
    #pragma unroll
    for (int i = 0; i < 32; ++i) {
        offs[base + i] = run;
        cursor[base + i] = run;
        run += loc[i];
    }
    float n = nsh;
    for (int k = t; k < NCODES; k += 256)
        s_out[k] = (out4[k] + EPSF) / (n + KEPSF) * n;
}

// ---------------------------------------------------------------------------
__global__ __launch_bounds__(256) void k_place(const int* __restrict__ widx,
                                               int* __restrict__ cursor,
                                               int* __restrict__ plist) {
    int p = blockIdx.x * 256 + threadIdx.x;
    int idx = widx[p];
    int slot = atomicAdd(&cursor[idx], 1);
    plist[slot] = p;
}

// ---------------------------------------------------------------------------
// z_q_st + commitment-loss partials (no atomics; one double per block)
__global__ __launch_bounds__(256) void k_zq(const float* __restrict__ z,
                                            const float* __restrict__ emb,
                                            const int* __restrict__ widx,
                                            float* __restrict__ out0,
                                            double* __restrict__ part) {
    __shared__ double sred[4];
    int w = (blockIdx.x * blockDim.x + threadIdx.x) >> 6;  // point id
    int wv = threadIdx.x >> 6;
    int lane = threadIdx.x & 63;
    int idx = widx[w];
    const float4 zv = *(const float4*)(z + (size_t)w * DIM + 4 * lane);
    const float4 ev = *(const float4*)(emb + (size_t)idx * DIM + 4 * lane);

    float4 o;
    o.x = ev.x + (zv.x - ev.x);
    o.y = ev.y + (zv.y - ev.y);
    o.z = ev.z + (zv.z - ev.z);
    o.w = ev.w + (zv.w - ev.w);
    *(float4*)(out0 + (size_t)w * DIM + 4 * lane) = o;

    float t0 = ev.x - zv.x, t1 = ev.y - zv.y, t2 = ev.z - zv.z, t3 = ev.w - zv.w;
    float s0 = t0 * t0, s1 = t1 * t1, s2 = t2 * t2, s3 = t3 * t3;
    double ls = (double)s0 + (double)s1 + (double)s2 + (double)s3;
    #pragma unroll
    for (int off = 32; off > 0; off >>= 1) ls += __shfl_down(ls, off);
    if (lane == 0) sred[wv] = ls;
    __syncthreads();
    if (threadIdx.x == 0)
        part[blockIdx.x] = (sred[0] + sred[1]) + (sred[2] + sred[3]);
}

// ---------------------------------------------------------------------------
// single block: sum 8192 loss partials -> out2
__global__ __launch_bounds__(256) void k_loss(const double* __restrict__ part,
                                              float* __restrict__ out2) {
    __shared__ double red[256];
    int t = threadIdx.x;
    double s = 0.0;
    for (int i = t; i < NPTS / 4; i += 256) s += part[i];
    red[t] = s;
    __syncthreads();
    for (int off = 128; off > 0; off >>= 1) {
        if (t < off) red[t] += red[t + off];
        __syncthreads();
    }
    if (t == 0)
        out2[0] = 0.25f * (float)(red[0] / (double)((size_t)NPTS * DIM));
}

// ---------------------------------------------------------------------------
// one wave per code: out5 = 0.99*eem + 0.01*sum(z[points of code])
__global__ __launch_bounds__(256) void k_dw(const float* __restrict__ z,
                                            const float* __restrict__ eem,
                                            const int* __restrict__ offs,
                                            const int* __restrict__ cnt,
                                            const int* __restrict__ plist,
                                            float* __restrict__ out5) {
    int c = blockIdx.x * 4 + (threadIdx.x >> 6);
    int lane = threadIdx.x & 63;
    int beg = offs[c], num = cnt[c];
    float4 acc = make_float4(0.f, 0.f, 0.f, 0.f);
    for (int j = 0; j < num; ++j) {
        int p = plist[beg + j];
        const float4 v = *(const float4*)(z + (size_t)p * DIM + 4 * lane);
        acc.x += v.x; acc.y += v.y; acc.z += v.z; acc.w += v.w;
    }
    const float4 e = *(const float4*)(eem + (size_t)c * DIM + 4 * lane);
    float4 o;
    o.x = e.x * DECAYF + acc.x * ONE_MINUS_DECAYF;
    o.y = e.y * DECAYF + acc.y * ONE_MINUS_DECAYF;
    o.z = e.z * DECAYF + acc.z * ONE_MINUS_DECAYF;
    o.w = e.w * DECAYF + acc.w * ONE_MINUS_DECAYF;
    *(float4*)(out5 + (size_t)c * DIM + 4 * lane) = o;
}

// ---------------------------------------------------------------------------
__global__ __launch_bounds__(256) void k_final(const float* __restrict__ out5,
                                               const float* __restrict__ s,
                                               float* __restrict__ out3) {
    int i = blockIdx.x * blockDim.x + threadIdx.x;
    int stride = gridDim.x * blockDim.x;
    for (int j = i; j < NCODES * DIM; j += stride)
        out3[j] = out5[j] / s[j >> 8];
}

// ---------------------------------------------------------------------------
extern "C" void kernel_launch(void* const* d_in, const int* in_sizes, int n_in,
                              void* d_out, int out_size, void* d_ws, size_t ws_size,
                              hipStream_t stream) {
    const float* z   = (const float*)d_in[0];
    const float* emb = (const float*)d_in[1];
    const float* ecs = (const float*)d_in[2];
    const float* eem = (const float*)d_in[3];

    float* out = (float*)d_out;
    float* out0 = out;                   // z_q_st         [8388608]
    float* out1 = out + 8388608;         // indices        [32768]
    float* out2 = out + 8421376;         // vq_loss        [1]
    float* out3 = out + 8421377;         // new_embedding  [2097152]
    float* out4 = out + 10518529;        // new_ema_cs     [8192]
    float* out5 = out + 10526721;        // new_ema_emb    [2097152]

    char* ws = (char*)d_ws;
    double* wPart = (double*)(ws + WS_PART);
    float*  wA    = (float*)(ws + WS_A);
    float*  wEn   = (float*)(ws + WS_EN);
    int*    wCnt  = (int*)(ws + WS_CNT);
    float*  wS    = (float*)(ws + WS_S);
    int*    wIdx  = (int*)(ws + WS_IDX);
    int*    wOffs = (int*)(ws + WS_OFFS);
    int*    wCur  = (int*)(ws + WS_CUR);
    int*    wPl   = (int*)(ws + WS_PLIST);
    float*  wGmin = (float*)(ws + WS_GMIN);
    unsigned short* wAh = (unsigned short*)(ws + WS_AH);
    unsigned short* wBh = (unsigned short*)(ws + WS_BH);

    hipLaunchKernelGGL(k_prep0, dim3(32), dim3(256), 0, stream, wCnt);
    hipLaunchKernelGGL(k_rownorm, dim3(NPTS / 4), dim3(256), 0, stream, z, wA, NPTS);
    hipLaunchKernelGGL(k_rownorm, dim3(NCODES / 4), dim3(256), 0, stream, emb, wEn, NCODES);
    hipLaunchKernelGGL(k_split, dim3(4096), dim3(256), 0, stream, z, wAh, NPTS * DIM);
    hipLaunchKernelGGL(k_split, dim3(1024), dim3(256), 0, stream, emb, wBh, NCODES * DIM);
    hipLaunchKernelGGL(k_gemm_argmin, dim3(512), dim3(512), 0, stream,
                       wAh, wBh, wEn, wGmin);
    hipLaunchKernelGGL(k_phase2, dim3(NPTS / 4), dim3(256), 0, stream,
                       z, emb, wA, wEn, wGmin, wIdx, out1, wCnt);
    hipLaunchKernelGGL(k_scan, dim3(1), dim3(256), 0, stream,
                       wCnt, ecs, wOffs, wCur, out4, wS);
    hipLaunchKernelGGL(k_place, dim3(NPTS / 256), dim3(256), 0, stream, wIdx, wCur, wPl);
    hipLaunchKernelGGL(k_zq, dim3(NPTS / 4), dim3(256), 0, stream, z, emb, wIdx, out0, wPart);
    hipLaunchKernelGGL(k_loss, dim3(1), dim3(256), 0, stream, wPart, out2);
    hipLaunchKernelGGL(k_dw, dim3(NCODES / 4), dim3(256), 0, stream,
                       z, eem, wOffs, wCnt, wPl, out5);
    hipLaunchKernelGGL(k_final, dim3(2048), dim3(256), 0, stream, out5, wS, out3);
}

// Round 4
// 368.818 us; speedup vs baseline: 1.3860x; 1.3860x over previous
//
#include <hip/hip_runtime.h>

#define NPTS   32768
#define NCODES 8192
#define DIM    256

#define DECAYF 0.99f
#define ONE_MINUS_DECAYF ((float)(1.0 - 0.99))
#define EPSF   1e-5f
#define KEPSF  ((float)(8192.0 * 1e-5))
#define MARGIN 0.05f

// workspace byte offsets
#define WS_PART  0                                     // fp64 [8192] loss partials
#define WS_A     (WS_PART + NPTS / 4 * 8)              // fp32 [NPTS]
#define WS_EN    (WS_A + NPTS * 4)                     // fp32 [NCODES]
#define WS_CNT   (WS_EN + NCODES * 4)                  // int  [NCODES]
#define WS_S     (WS_CNT + NCODES * 4)                 // fp32 [NCODES] smoothed
#define WS_IDX   (WS_S + NCODES * 4)                   // int  [NPTS]
#define WS_OFFS  (WS_IDX + NPTS * 4)                   // int  [NCODES]
#define WS_CUR   (WS_OFFS + NCODES * 4)                // int  [NCODES]
#define WS_PLIST (WS_CUR + NCODES * 4)                 // int  [NPTS]
#define WS_EMBT  (WS_PLIST + NPTS * 4)                 // (unused, kept for layout)
#define WS_GMIN  (WS_EMBT + (size_t)DIM * NCODES * 4)  // fp32 [NPTS][512]     64 MB
#define WS_AH    (WS_GMIN + (size_t)NPTS * 512 * 4)    // bf16 [NPTS][256]     16 MB
#define WS_BH    (WS_AH + (size_t)NPTS * DIM * 2)      // bf16 [NCODES][256]    4 MB

typedef __attribute__((ext_vector_type(8))) short short8;
typedef __attribute__((ext_vector_type(4))) float f32x4;

__device__ inline void gl_lds16(const void* g, void* l) {
    __builtin_amdgcn_global_load_lds(
        (const __attribute__((address_space(1))) void*)g,
        (__attribute__((address_space(3))) void*)l, 16, 0, 0);
}

__device__ inline unsigned short f2bf(float f) {  // RNE float->bf16
    unsigned u = __float_as_uint(f);
    return (unsigned short)((u + 0x7FFFu + ((u >> 16) & 1u)) >> 16);
}
__device__ inline unsigned f2ord(float f) {       // monotone float->uint
    unsigned u = __float_as_uint(f);
    return (u & 0x80000000u) ? ~u : (u | 0x80000000u);
}

// ---------------------------------------------------------------------------
__global__ __launch_bounds__(256) void k_prep0(int* __restrict__ cnt) {
    int i = blockIdx.x * blockDim.x + threadIdx.x;
    if (i < NCODES) cnt[i] = 0;
}

// ---------------------------------------------------------------------------
// Fused: row squared-norm + fp32 -> bf16-hi copy (one read of x serves both).
__global__ __launch_bounds__(256) void k_rownorm_split(
    const float* __restrict__ x, float* __restrict__ outn,
    unsigned short* __restrict__ dst, int nrows) {
    int w = (blockIdx.x * blockDim.x + threadIdx.x) >> 6;
    int lane = threadIdx.x & 63;
    if (w >= nrows) return;
    const float4 v = *(const float4*)(x + (size_t)w * DIM + 4 * lane);
    ushort4 h;
    h.x = f2bf(v.x); h.y = f2bf(v.y); h.z = f2bf(v.z); h.w = f2bf(v.w);
    *(ushort4*)(dst + (size_t)w * DIM + 4 * lane) = h;
    float q0 = v.x * v.x, q1 = v.y * v.y, q2 = v.z * v.z, q3 = v.w * v.w;
    double s = (double)q0 + (double)q1 + (double)q2 + (double)q3;
    #pragma unroll
    for (int off = 32; off > 0; off >>= 1) s += __shfl_down(s, off);
    if (lane == 0) outn[w] = (float)s;
}

// ---------------------------------------------------------------------------
// Phase 1: bf16-hi MFMA GEMM (M=32768, N=8192, K=256), fused epilogue writes
// per-16-code-group approx min distance (float) to gmin[NPTS][512].
// (Round-1 structure: 128x128 tile, 4 waves, 32KB LDS -- measured 157us/871TF,
// at its structure ceiling; deeper pipelines measured WORSE on this shape.)
__global__ __launch_bounds__(256) void k_gemm_argmin(
    const unsigned short* __restrict__ Ah,    // [NPTS][256] bf16 bits
    const unsigned short* __restrict__ Bh,    // [NCODES][256] bf16 bits
    const float* __restrict__ en,
    float* __restrict__ gmin) {               // [NPTS][512]
    __shared__ __align__(16) unsigned short SBUF[16384];  // 32 KB: A | B

    const int t = threadIdx.x;
    const int w = t >> 6, l = t & 63;
    const int quad = l >> 4, l15 = l & 15;
    const int wr = w >> 1, wc = w & 1;
    const int mb = blockIdx.x >> 6, nb = blockIdx.x & 63;
    const int mBase = mb * 128, nBase = nb * 128;

    // staging swizzle: slot s covers (row=s>>3, x=s&7, kchunk = x ^ (row&7))
    const int xr = (t & 7) ^ ((t >> 3) & 7);
    const int rrow = t >> 3;
    const unsigned short* ag[4];
    const unsigned short* bg[4];
    #pragma unroll
    for (int i = 0; i < 4; ++i) {
        ag[i] = Ah + (size_t)(mBase + i * 32 + rrow) * DIM + xr * 8;
        bg[i] = Bh + (size_t)(nBase + i * 32 + rrow) * DIM + xr * 8;
    }

    f32x4 acc[4][4];
    #pragma unroll
    for (int i = 0; i < 4; ++i)
        #pragma unroll
        for (int j = 0; j < 4; ++j)
            acc[i][j] = (f32x4){0.f, 0.f, 0.f, 0.f};

    for (int kt = 0; kt < 4; ++kt) {
        __syncthreads();
        #pragma unroll
        for (int i = 0; i < 4; ++i) {
            gl_lds16(ag[i], &SBUF[(i * 256 + w * 64) * 8]);
            gl_lds16(bg[i], &SBUF[8192 + (i * 256 + w * 64) * 8]);
            ag[i] += 64; bg[i] += 64;
        }
        __syncthreads();
        #pragma unroll
        for (int kk = 0; kk < 2; ++kk) {
            const int kc = kk * 4 + quad;
            short8 a[4], b[4];
            #pragma unroll
            for (int ti = 0; ti < 4; ++ti) {
                int m = wr * 64 + ti * 16 + l15;
                a[ti] = *(const short8*)&SBUF[(m * 8 + (kc ^ (m & 7))) * 8];
                int n = wc * 64 + ti * 16 + l15;
                b[ti] = *(const short8*)&SBUF[8192 + (n * 8 + (kc ^ (n & 7))) * 8];
            }
            #pragma unroll
            for (int ti = 0; ti < 4; ++ti)
                #pragma unroll
                for (int tj = 0; tj < 4; ++tj)
                    acc[ti][tj] = __builtin_amdgcn_mfma_f32_16x16x32_bf16(
                        a[ti], b[tj], acc[ti][tj], 0, 0, 0);
        }
    }

    // epilogue: per-lane min over tj, stage in freed staging LDS, then
    // 16-code group minima to gmin.
    float enc[4];
    #pragma unroll
    for (int tj = 0; tj < 4; ++tj)
        enc[tj] = en[nBase + wc * 64 + tj * 16 + l15];

    __syncthreads();
    float* ov = (float*)SBUF;   // [2][128][16] = 16 KB
    #pragma unroll
    for (int ti = 0; ti < 4; ++ti) {
        #pragma unroll
        for (int r = 0; r < 4; ++r) {
            float dmin = enc[0] - 2.0f * acc[ti][0][r];
            #pragma unroll
            for (int tj = 1; tj < 4; ++tj)
                dmin = fminf(dmin, enc[tj] - 2.0f * acc[ti][tj][r]);
            int p = wr * 64 + ti * 16 + quad * 4 + r;
            ov[(wc * 128 + p) * 16 + l15] = dmin;
        }
    }
    __syncthreads();
    #pragma unroll
    for (int it = 0; it < 4; ++it) {
        int id = it * 256 + t;                 // (wcc*128 + p)*4 + sg
        int sg = id & 3;
        const float4 v = *(const float4*)&ov[(id >> 2) * 16 + sg * 4];
        float m = fminf(fminf(v.x, v.y), fminf(v.z, v.w));
        int pp = (id >> 2) & 127;
        int wcc = id >> 9;
        gmin[(size_t)(mBase + pp) * 512 + nb * 8 + wcc * 4 + sg] = m;
    }
}

// ---------------------------------------------------------------------------
// Phase 2 (FUSED with z_q_st + commitment-loss partials): one wave per point.
// Approx global min over 512 group minima; rescore flagged groups exactly in
// fp32 reading emb ROWS cooperatively (coalesced, butterfly-reduced). After
// the final reduce ALL lanes hold the winning (dist,idx), and z4 is already
// in registers -> write the straight-through row + loss partial here (k_zq's
// exact fp32 expression order), deleting the separate k_zq pass.
__global__ __launch_bounds__(256) void k_phase2(
    const float* __restrict__ z, const float* __restrict__ emb,
    const float* __restrict__ A, const float* __restrict__ en,
    const float* __restrict__ gmin,
    int* __restrict__ widx, float* __restrict__ out1,
    int* __restrict__ cnt, float* __restrict__ out0,
    double* __restrict__ part) {
    __shared__ double sred[4];
    int wv = threadIdx.x >> 6;
    int wpt = (blockIdx.x << 2) + wv;  // point id
    int l = threadIdx.x & 63;

    const float* gp = gmin + (size_t)wpt * 512;
    float loc[8];
    #pragma unroll
    for (int i = 0; i < 8; ++i) loc[i] = gp[i * 64 + l];
    float m8 = loc[0];
    #pragma unroll
    for (int i = 1; i < 8; ++i) m8 = fminf(m8, loc[i]);
    #pragma unroll
    for (int off = 1; off < 64; off <<= 1) m8 = fminf(m8, __shfl_xor(m8, off));
    const float thresh = m8 + MARGIN;

    const float4 z4 = *(const float4*)(z + (size_t)wpt * DIM + 4 * l);
    const float Azn = A[wpt];
    unsigned long long best = ~0ull;
    #pragma unroll 1
    for (int i = 0; i < 8; ++i) {
        unsigned long long mask = __ballot(loc[i] <= thresh);
        while (mask) {
            int s = __ffsll((long long)mask) - 1;
            mask &= mask - 1;
            int gid = i * 64 + s;
            int cbase = (gid >> 3) * 128 + ((gid >> 2) & 1) * 64 + (gid & 3) * 4;
            #pragma unroll 4
            for (int k = 0; k < 16; ++k) {
                int c = cbase + (k >> 2) * 16 + (k & 3);
                const float4 ev = *(const float4*)(emb + (size_t)c * DIM + 4 * l);
                float p = fmaf(z4.x, ev.x,
                          fmaf(z4.y, ev.y,
                          fmaf(z4.z, ev.z, z4.w * ev.w)));
                #pragma unroll
                for (int off = 1; off < 64; off <<= 1) p += __shfl_xor(p, off);
                float dist = (Azn - 2.0f * p) + en[c];
                unsigned long long pk =
                    ((unsigned long long)f2ord(dist) << 32) | (unsigned)c;
                best = pk < best ? pk : best;
            }
        }
    }
    const int idx = (int)(unsigned)best;   // all lanes agree post-reduce
    if (l == 0) {
        widx[wpt] = idx;
        out1[wpt] = (float)idx;
        atomicAdd(cnt + idx, 1);
    }

    // ---- fused z_q_st + loss partial (k_zq semantics, verbatim order)
    const float4 ev = *(const float4*)(emb + (size_t)idx * DIM + 4 * l);
    float4 o;
    o.x = ev.x + (z4.x - ev.x);
    o.y = ev.y + (z4.y - ev.y);
    o.z = ev.z + (z4.z - ev.z);
    o.w = ev.w + (z4.w - ev.w);
    *(float4*)(out0 + (size_t)wpt * DIM + 4 * l) = o;

    float t0 = ev.x - z4.x, t1 = ev.y - z4.y, t2 = ev.z - z4.z, t3 = ev.w - z4.w;
    float s0 = t0 * t0, s1 = t1 * t1, s2 = t2 * t2, s3 = t3 * t3;
    double ls = (double)s0 + (double)s1 + (double)s2 + (double)s3;
    #pragma unroll
    for (int off = 32; off > 0; off >>= 1) ls += __shfl_down(ls, off);
    if (l == 0) sred[wv] = ls;
    __syncthreads();
    if (threadIdx.x == 0)
        part[blockIdx.x] = (sred[0] + sred[1]) + (sred[2] + sred[3]);
}

// ---------------------------------------------------------------------------
// single block: exclusive prefix of cnt -> offs (+cursor copy);
// out4 = ecs*0.99 + cnt*0.01; n = sum(out4); smoothed -> s_out.
__global__ __launch_bounds__(256) void k_scan(const int* __restrict__ cnt,
                                              const float* __restrict__ ecs,
                                              int* __restrict__ offs,
                                              int* __restrict__ cursor,
                                              float* __restrict__ out4,
                                              float* __restrict__ s_out) {
    __shared__ int ps[256];
    __shared__ double rd[256];
    __shared__ float nsh;
    int t = threadIdx.x;
    int base = t * 32;
    int loc[32];
    int s = 0;
    double nl = 0.0;
    #pragma unroll
    for (int i = 0; i < 32; ++i) {
        int c = cnt[base + i];
        loc[i] = c;
        s += c;
        float f = ecs[base + i] * DECAYF + (float)c * ONE_MINUS_DECAYF;
        out4[base + i] = f;
        nl += (double)f;
    }
    ps[t] = s;
    rd[t] = nl;
    __syncthreads();
    for (int off = 1; off < 256; off <<= 1) {
        int v = (t >= off) ? ps[t - off] : 0;
        __syncthreads();
        ps[t] += v;
        __syncthreads();
    }
    for (int off = 128; off > 0; off >>= 1) {
        if (t < off) rd[t] += rd[t + off];
        __syncthreads();
    }
    if (t == 0) nsh = (float)rd[0];
    __syncthreads();
    int run = (t == 0) ? 0 : ps[t - 1];
    #pragma unroll
    for (int i = 0; i < 32; ++i) {
        offs[base + i] = run;
        cursor[base + i] = run;
        run += loc[i];
    }
    float n = nsh;
    for (int k = t; k < NCODES; k += 256)
        s_out[k] = (out4[k] + EPSF) / (n + KEPSF) * n;
}

// ---------------------------------------------------------------------------
__global__ __launch_bounds__(256) void k_place(const int* __restrict__ widx,
                                               int* __restrict__ cursor,
                                               int* __restrict__ plist) {
    int p = blockIdx.x * 256 + threadIdx.x;
    int idx = widx[p];
    int slot = atomicAdd(&cursor[idx], 1);
    plist[slot] = p;
}

// ---------------------------------------------------------------------------
// single block: sum 8192 loss partials -> out2
__global__ __launch_bounds__(256) void k_loss(const double* __restrict__ part,
                                              float* __restrict__ out2) {
    __shared__ double red[256];
    int t = threadIdx.x;
    double s = 0.0;
    for (int i = t; i < NPTS / 4; i += 256) s += part[i];
    red[t] = s;
    __syncthreads();
    for (int off = 128; off > 0; off >>= 1) {
        if (t < off) red[t] += red[t + off];
        __syncthreads();
    }
    if (t == 0)
        out2[0] = 0.25f * (float)(red[0] / (double)((size_t)NPTS * DIM));
}

// ---------------------------------------------------------------------------
// one wave per code: out5 = 0.99*eem + 0.01*sum(z[points of code])
__global__ __launch_bounds__(256) void k_dw(const float* __restrict__ z,
                                            const float* __restrict__ eem,
                                            const int* __restrict__ offs,
                                            const int* __restrict__ cnt,
                                            const int* __restrict__ plist,
                                            float* __restrict__ out5) {
    int c = blockIdx.x * 4 + (threadIdx.x >> 6);
    int lane = threadIdx.x & 63;
    int beg = offs[c], num = cnt[c];
    float4 acc = make_float4(0.f, 0.f, 0.f, 0.f);
    for (int j = 0; j < num; ++j) {
        int p = plist[beg + j];
        const float4 v = *(const float4*)(z + (size_t)p * DIM + 4 * lane);
        acc.x += v.x; acc.y += v.y; acc.z += v.z; acc.w += v.w;
    }
    const float4 e = *(const float4*)(eem + (size_t)c * DIM + 4 * lane);
    float4 o;
    o.x = e.x * DECAYF + acc.x * ONE_MINUS_DECAYF;
    o.y = e.y * DECAYF + acc.y * ONE_MINUS_DECAYF;
    o.z = e.z * DECAYF + acc.z * ONE_MINUS_DECAYF;
    o.w = e.w * DECAYF + acc.w * ONE_MINUS_DECAYF;
    *(float4*)(out5 + (size_t)c * DIM + 4 * lane) = o;
}

// ---------------------------------------------------------------------------
__global__ __launch_bounds__(256) void k_final(const float* __restrict__ out5,
                                               const float* __restrict__ s,
                                               float* __restrict__ out3) {
    int i = blockIdx.x * blockDim.x + threadIdx.x;
    int stride = gridDim.x * blockDim.x;
    for (int j = i; j < NCODES * DIM; j += stride)
        out3[j] = out5[j] / s[j >> 8];
}

// ---------------------------------------------------------------------------
extern "C" void kernel_launch(void* const* d_in, const int* in_sizes, int n_in,
                              void* d_out, int out_size, void* d_ws, size_t ws_size,
                              hipStream_t stream) {
    const float* z   = (const float*)d_in[0];
    const float* emb = (const float*)d_in[1];
    const float* ecs = (const float*)d_in[2];
    const float* eem = (const float*)d_in[3];

    float* out = (float*)d_out;
    float* out0 = out;                   // z_q_st         [8388608]
    float* out1 = out + 8388608;         // indices        [32768]
    float* out2 = out + 8421376;         // vq_loss        [1]
    float* out3 = out + 8421377;         // new_embedding  [2097152]
    float* out4 = out + 10518529;        // new_ema_cs     [8192]
    float* out5 = out + 10526721;        // new_ema_emb    [2097152]

    char* ws = (char*)d_ws;
    double* wPart = (double*)(ws + WS_PART);
    float*  wA    = (float*)(ws + WS_A);
    float*  wEn   = (float*)(ws + WS_EN);
    int*    wCnt  = (int*)(ws + WS_CNT);
    float*  wS    = (float*)(ws + WS_S);
    int*    wIdx  = (int*)(ws + WS_IDX);
    int*    wOffs = (int*)(ws + WS_OFFS);
    int*    wCur  = (int*)(ws + WS_CUR);
    int*    wPl   = (int*)(ws + WS_PLIST);
    float*  wGmin = (float*)(ws + WS_GMIN);
    unsigned short* wAh = (unsigned short*)(ws + WS_AH);
    unsigned short* wBh = (unsigned short*)(ws + WS_BH);

    hipLaunchKernelGGL(k_prep0, dim3(32), dim3(256), 0, stream, wCnt);
    hipLaunchKernelGGL(k_rownorm_split, dim3(NPTS / 4), dim3(256), 0, stream,
                       z, wA, wAh, NPTS);
    hipLaunchKernelGGL(k_rownorm_split, dim3(NCODES / 4), dim3(256), 0, stream,
                       emb, wEn, wBh, NCODES);
    hipLaunchKernelGGL(k_gemm_argmin, dim3((NPTS / 128) * (NCODES / 128)), dim3(256), 0, stream,
                       wAh, wBh, wEn, wGmin);
    hipLaunchKernelGGL(k_phase2, dim3(NPTS / 4), dim3(256), 0, stream,
                       z, emb, wA, wEn, wGmin, wIdx, out1, wCnt, out0, wPart);
    hipLaunchKernelGGL(k_scan, dim3(1), dim3(256), 0, stream,
                       wCnt, ecs, wOffs, wCur, out4, wS);
    hipLaunchKernelGGL(k_place, dim3(NPTS / 256), dim3(256), 0, stream, wIdx, wCur, wPl);
    hipLaunchKernelGGL(k_loss, dim3(1), dim3(256), 0, stream, wPart, out2);
    hipLaunchKernelGGL(k_dw, dim3(NCODES / 4), dim3(256), 0, stream,
                       z, eem, wOffs, wCnt, wPl, out5);
    hipLaunchKernelGGL(k_final, dim3(2048), dim3(256), 0, stream, out5, wS, out3);
}

// Round 5
// 352.668 us; speedup vs baseline: 1.4495x; 1.0458x over previous
//
#include <hip/hip_runtime.h>

#define NPTS   32768
#define NCODES 8192
#define DIM    256

#define DECAYF 0.99f
#define ONE_MINUS_DECAYF ((float)(1.0 - 0.99))
#define EPSF   1e-5f
#define KEPSF  ((float)(8192.0 * 1e-5))
#define MARGIN 0.05f

// workspace byte offsets
#define WS_PART  0                                     // fp64 [8192] loss partials
#define WS_A     (WS_PART + NPTS / 4 * 8)              // fp32 [NPTS]
#define WS_EN    (WS_A + NPTS * 4)                     // fp32 [NCODES]
#define WS_CNT   (WS_EN + NCODES * 4)                  // int  [NCODES]
#define WS_S     (WS_CNT + NCODES * 4)                 // fp32 [NCODES] smoothed
#define WS_IDX   (WS_S + NCODES * 4)                   // int  [NPTS]
#define WS_OFFS  (WS_IDX + NPTS * 4)                   // int  [NCODES]
#define WS_CUR   (WS_OFFS + NCODES * 4)                // int  [NCODES]
#define WS_PLIST (WS_CUR + NCODES * 4)                 // int  [NPTS]
#define WS_EMBT  (WS_PLIST + NPTS * 4)                 // (unused, kept for layout)
#define WS_GMIN  (WS_EMBT + (size_t)DIM * NCODES * 4)  // fp32 [NPTS][512]     64 MB
#define WS_AH    (WS_GMIN + (size_t)NPTS * 512 * 4)    // bf16 [NPTS][256]     16 MB
#define WS_BH    (WS_AH + (size_t)NPTS * DIM * 2)      // bf16 [NCODES][256]    4 MB

typedef __attribute__((ext_vector_type(8))) short short8;
typedef __attribute__((ext_vector_type(4))) float f32x4;

__device__ inline void gl_lds16(const void* g, void* l) {
    __builtin_amdgcn_global_load_lds(
        (const __attribute__((address_space(1))) void*)g,
        (__attribute__((address_space(3))) void*)l, 16, 0, 0);
}

__device__ inline unsigned short f2bf(float f) {  // RNE float->bf16
    unsigned u = __float_as_uint(f);
    return (unsigned short)((u + 0x7FFFu + ((u >> 16) & 1u)) >> 16);
}
__device__ inline unsigned f2ord(float f) {       // monotone float->uint
    unsigned u = __float_as_uint(f);
    return (u & 0x80000000u) ? ~u : (u | 0x80000000u);
}

// ---------------------------------------------------------------------------
// Fused prep: row squared-norm + fp32->bf16-hi copy for BOTH z and emb, plus
// cnt zeroing (one launch replaces 3). Block-uniform branch on blockIdx.
__device__ __forceinline__ void rownorm_split_row(
    const float* __restrict__ x, float* __restrict__ outn,
    unsigned short* __restrict__ dst, int w, int lane) {
    const float4 v = *(const float4*)(x + (size_t)w * DIM + 4 * lane);
    ushort4 h;
    h.x = f2bf(v.x); h.y = f2bf(v.y); h.z = f2bf(v.z); h.w = f2bf(v.w);
    *(ushort4*)(dst + (size_t)w * DIM + 4 * lane) = h;
    float q0 = v.x * v.x, q1 = v.y * v.y, q2 = v.z * v.z, q3 = v.w * v.w;
    double s = (double)q0 + (double)q1 + (double)q2 + (double)q3;
    #pragma unroll
    for (int off = 32; off > 0; off >>= 1) s += __shfl_down(s, off);
    if (lane == 0) outn[w] = (float)s;
}

__global__ __launch_bounds__(256) void k_prep(
    const float* __restrict__ z, const float* __restrict__ emb,
    float* __restrict__ wA, unsigned short* __restrict__ wAh,
    float* __restrict__ wEn, unsigned short* __restrict__ wBh,
    int* __restrict__ cnt) {
    const int b = blockIdx.x;
    const int lane = threadIdx.x & 63;
    if (b < NPTS / 4) {
        int w = (b * 256 + (int)threadIdx.x) >> 6;
        rownorm_split_row(z, wA, wAh, w, lane);
    } else {
        int b2 = b - NPTS / 4;
        if (b2 < 32) cnt[b2 * 256 + threadIdx.x] = 0;
        int w = (b2 * 256 + (int)threadIdx.x) >> 6;
        rownorm_split_row(emb, wEn, wBh, w, lane);
    }
}

// ---------------------------------------------------------------------------
// Phase 1: bf16-hi MFMA GEMM (M=32768, N=8192, K=256), fused epilogue writes
// per-16-code-group approx min distance (float) to gmin[NPTS][512].
// (128x128 tile, 4 waves, 32KB LDS -- measured 157us/871TF, at this
// structure's ceiling; deeper pipelines measured WORSE on this shape.)
// Epilogue staging stride = 20 floats: quads land 16 banks apart (2-way =
// free) instead of stride-16's 4-way conflict; float4 reads stay 16B-aligned.
__global__ __launch_bounds__(256) void k_gemm_argmin(
    const unsigned short* __restrict__ Ah,    // [NPTS][256] bf16 bits
    const unsigned short* __restrict__ Bh,    // [NCODES][256] bf16 bits
    const float* __restrict__ en,
    float* __restrict__ gmin) {               // [NPTS][512]
    __shared__ __align__(16) unsigned short SBUF[16384];  // 32 KB: A | B

    const int t = threadIdx.x;
    const int w = t >> 6, l = t & 63;
    const int quad = l >> 4, l15 = l & 15;
    const int wr = w >> 1, wc = w & 1;
    const int mb = blockIdx.x >> 6, nb = blockIdx.x & 63;
    const int mBase = mb * 128, nBase = nb * 128;

    // staging swizzle: slot s covers (row=s>>3, x=s&7, kchunk = x ^ (row&7))
    const int xr = (t & 7) ^ ((t >> 3) & 7);
    const int rrow = t >> 3;
    const unsigned short* ag[4];
    const unsigned short* bg[4];
    #pragma unroll
    for (int i = 0; i < 4; ++i) {
        ag[i] = Ah + (size_t)(mBase + i * 32 + rrow) * DIM + xr * 8;
        bg[i] = Bh + (size_t)(nBase + i * 32 + rrow) * DIM + xr * 8;
    }

    f32x4 acc[4][4];
    #pragma unroll
    for (int i = 0; i < 4; ++i)
        #pragma unroll
        for (int j = 0; j < 4; ++j)
            acc[i][j] = (f32x4){0.f, 0.f, 0.f, 0.f};

    for (int kt = 0; kt < 4; ++kt) {
        __syncthreads();
        #pragma unroll
        for (int i = 0; i < 4; ++i) {
            gl_lds16(ag[i], &SBUF[(i * 256 + w * 64) * 8]);
            gl_lds16(bg[i], &SBUF[8192 + (i * 256 + w * 64) * 8]);
            ag[i] += 64; bg[i] += 64;
        }
        __syncthreads();
        #pragma unroll
        for (int kk = 0; kk < 2; ++kk) {
            const int kc = kk * 4 + quad;
            short8 a[4], b[4];
            #pragma unroll
            for (int ti = 0; ti < 4; ++ti) {
                int m = wr * 64 + ti * 16 + l15;
                a[ti] = *(const short8*)&SBUF[(m * 8 + (kc ^ (m & 7))) * 8];
                int n = wc * 64 + ti * 16 + l15;
                b[ti] = *(const short8*)&SBUF[8192 + (n * 8 + (kc ^ (n & 7))) * 8];
            }
            #pragma unroll
            for (int ti = 0; ti < 4; ++ti)
                #pragma unroll
                for (int tj = 0; tj < 4; ++tj)
                    acc[ti][tj] = __builtin_amdgcn_mfma_f32_16x16x32_bf16(
                        a[ti], b[tj], acc[ti][tj], 0, 0, 0);
        }
    }

    // epilogue: per-lane min over tj, stage in freed staging LDS, then
    // 16-code group minima to gmin.
    float enc[4];
    #pragma unroll
    for (int tj = 0; tj < 4; ++tj)
        enc[tj] = en[nBase + wc * 64 + tj * 16 + l15];

    __syncthreads();
    float* ov = (float*)SBUF;   // [2][128][20] = 20 KB (stride 20, see above)
    #pragma unroll
    for (int ti = 0; ti < 4; ++ti) {
        #pragma unroll
        for (int r = 0; r < 4; ++r) {
            float dmin = enc[0] - 2.0f * acc[ti][0][r];
            #pragma unroll
            for (int tj = 1; tj < 4; ++tj)
                dmin = fminf(dmin, enc[tj] - 2.0f * acc[ti][tj][r]);
            int p = wr * 64 + ti * 16 + quad * 4 + r;
            ov[(wc * 128 + p) * 20 + l15] = dmin;
        }
    }
    __syncthreads();
    #pragma unroll
    for (int it = 0; it < 4; ++it) {
        int id = it * 256 + t;                 // (wcc*128 + p)*4 + sg
        int sg = id & 3;
        const float4 v = *(const float4*)&ov[(id >> 2) * 20 + sg * 4];
        float m = fminf(fminf(v.x, v.y), fminf(v.z, v.w));
        int pp = (id >> 2) & 127;
        int wcc = id >> 9;
        gmin[(size_t)(mBase + pp) * 512 + nb * 8 + wcc * 4 + sg] = m;
    }
}

// ---------------------------------------------------------------------------
// Phase 2 (FUSED with z_q_st + commitment-loss partials): one wave per point.
// Approx global min over 512 group minima; rescore flagged groups exactly in
// fp32 reading emb ROWS cooperatively (coalesced, butterfly-reduced). After
// the final reduce ALL lanes hold the winning (dist,idx), and z4 is already
// in registers -> write the straight-through row + loss partial here.
__global__ __launch_bounds__(256) void k_phase2(
    const float* __restrict__ z, const float* __restrict__ emb,
    const float* __restrict__ A, const float* __restrict__ en,
    const float* __restrict__ gmin,
    int* __restrict__ widx, float* __restrict__ out1,
    int* __restrict__ cnt, float* __restrict__ out0,
    double* __restrict__ part) {
    __shared__ double sred[4];
    int wv = threadIdx.x >> 6;
    int wpt = (blockIdx.x << 2) + wv;  // point id
    int l = threadIdx.x & 63;

    const float* gp = gmin + (size_t)wpt * 512;
    float loc[8];
    #pragma unroll
    for (int i = 0; i < 8; ++i) loc[i] = gp[i * 64 + l];
    float m8 = loc[0];
    #pragma unroll
    for (int i = 1; i < 8; ++i) m8 = fminf(m8, loc[i]);
    #pragma unroll
    for (int off = 1; off < 64; off <<= 1) m8 = fminf(m8, __shfl_xor(m8, off));
    const float thresh = m8 + MARGIN;

    const float4 z4 = *(const float4*)(z + (size_t)wpt * DIM + 4 * l);
    const float Azn = A[wpt];
    unsigned long long best = ~0ull;
    #pragma unroll 1
    for (int i = 0; i < 8; ++i) {
        unsigned long long mask = __ballot(loc[i] <= thresh);
        while (mask) {
            int s = __ffsll((long long)mask) - 1;
            mask &= mask - 1;
            int gid = i * 64 + s;
            int cbase = (gid >> 3) * 128 + ((gid >> 2) & 1) * 64 + (gid & 3) * 4;
            #pragma unroll 4
            for (int k = 0; k < 16; ++k) {
                int c = cbase + (k >> 2) * 16 + (k & 3);
                const float4 ev = *(const float4*)(emb + (size_t)c * DIM + 4 * l);
                float p = fmaf(z4.x, ev.x,
                          fmaf(z4.y, ev.y,
                          fmaf(z4.z, ev.z, z4.w * ev.w)));
                #pragma unroll
                for (int off = 1; off < 64; off <<= 1) p += __shfl_xor(p, off);
                float dist = (Azn - 2.0f * p) + en[c];
                unsigned long long pk =
                    ((unsigned long long)f2ord(dist) << 32) | (unsigned)c;
                best = pk < best ? pk : best;
            }
        }
    }
    const int idx = (int)(unsigned)best;   // all lanes agree post-reduce
    if (l == 0) {
        widx[wpt] = idx;
        out1[wpt] = (float)idx;
        atomicAdd(cnt + idx, 1);
    }

    // ---- fused z_q_st + loss partial (k_zq semantics, verbatim order)
    const float4 ev = *(const float4*)(emb + (size_t)idx * DIM + 4 * l);
    float4 o;
    o.x = ev.x + (z4.x - ev.x);
    o.y = ev.y + (z4.y - ev.y);
    o.z = ev.z + (z4.z - ev.z);
    o.w = ev.w + (z4.w - ev.w);
    *(float4*)(out0 + (size_t)wpt * DIM + 4 * l) = o;

    float t0 = ev.x - z4.x, t1 = ev.y - z4.y, t2 = ev.z - z4.z, t3 = ev.w - z4.w;
    float s0 = t0 * t0, s1 = t1 * t1, s2 = t2 * t2, s3 = t3 * t3;
    double ls = (double)s0 + (double)s1 + (double)s2 + (double)s3;
    #pragma unroll
    for (int off = 32; off > 0; off >>= 1) ls += __shfl_down(ls, off);
    if (l == 0) sred[wv] = ls;
    __syncthreads();
    if (threadIdx.x == 0)
        part[blockIdx.x] = (sred[0] + sred[1]) + (sred[2] + sred[3]);
}

// ---------------------------------------------------------------------------
// single block: exclusive prefix of cnt -> offs (+cursor copy);
// out4 = ecs*0.99 + cnt*0.01; n = sum(out4); smoothed -> s_out.
// FUSED: loss partial sum -> out2 (identical summation order to old k_loss).
__global__ __launch_bounds__(256) void k_scan(const int* __restrict__ cnt,
                                              const float* __restrict__ ecs,
                                              int* __restrict__ offs,
                                              int* __restrict__ cursor,
                                              float* __restrict__ out4,
                                              float* __restrict__ s_out,
                                              const double* __restrict__ part,
                                              float* __restrict__ out2) {
    __shared__ int ps[256];
    __shared__ double rd[256];
    __shared__ float nsh;
    int t = threadIdx.x;
    int base = t * 32;
    int loc[32];
    int s = 0;
    double nl = 0.0;
    #pragma unroll
    for (int i = 0; i < 32; ++i) {
        int c = cnt[base + i];
        loc[i] = c;
        s += c;
        float f = ecs[base + i] * DECAYF + (float)c * ONE_MINUS_DECAYF;
        out4[base + i] = f;
        nl += (double)f;
    }
    ps[t] = s;
    rd[t] = nl;
    __syncthreads();
    for (int off = 1; off < 256; off <<= 1) {
        int v = (t >= off) ? ps[t - off] : 0;
        __syncthreads();
        ps[t] += v;
        __syncthreads();
    }
    for (int off = 128; off > 0; off >>= 1) {
        if (t < off) rd[t] += rd[t + off];
        __syncthreads();
    }
    if (t == 0) nsh = (float)rd[0];
    __syncthreads();
    int run = (t == 0) ? 0 : ps[t - 1];
    #pragma unroll
    for (int i = 0; i < 32; ++i) {
        offs[base + i] = run;
        cursor[base + i] = run;
        run += loc[i];
    }
    float n = nsh;
    for (int k = t; k < NCODES; k += 256)
        s_out[k] = (out4[k] + EPSF) / (n + KEPSF) * n;

    // ---- fused loss reduction (old k_loss, bit-identical order)
    __syncthreads();
    double lsum = 0.0;
    for (int i = t; i < NPTS / 4; i += 256) lsum += part[i];
    rd[t] = lsum;
    __syncthreads();
    for (int off = 128; off > 0; off >>= 1) {
        if (t < off) rd[t] += rd[t + off];
        __syncthreads();
    }
    if (t == 0)
        out2[0] = 0.25f * (float)(rd[0] / (double)((size_t)NPTS * DIM));
}

// ---------------------------------------------------------------------------
__global__ __launch_bounds__(256) void k_place(const int* __restrict__ widx,
                                               int* __restrict__ cursor,
                                               int* __restrict__ plist) {
    int p = blockIdx.x * 256 + threadIdx.x;
    int idx = widx[p];
    int slot = atomicAdd(&cursor[idx], 1);
    plist[slot] = p;
}

// ---------------------------------------------------------------------------
// one wave per code: out5 = 0.99*eem + 0.01*sum(z[points of code]);
// FUSED: out3 = out5 / smoothed[c]  (old k_final).
__global__ __launch_bounds__(256) void k_dw(const float* __restrict__ z,
                                            const float* __restrict__ eem,
                                            const int* __restrict__ offs,
                                            const int* __restrict__ cnt,
                                            const int* __restrict__ plist,
                                            const float* __restrict__ s,
                                            float* __restrict__ out5,
                                            float* __restrict__ out3) {
    int c = blockIdx.x * 4 + (threadIdx.x >> 6);
    int lane = threadIdx.x & 63;
    int beg = offs[c], num = cnt[c];
    float4 acc = make_float4(0.f, 0.f, 0.f, 0.f);
    for (int j = 0; j < num; ++j) {
        int p = plist[beg + j];
        const float4 v = *(const float4*)(z + (size_t)p * DIM + 4 * lane);
        acc.x += v.x; acc.y += v.y; acc.z += v.z; acc.w += v.w;
    }
    const float4 e = *(const float4*)(eem + (size_t)c * DIM + 4 * lane);
    float4 o;
    o.x = e.x * DECAYF + acc.x * ONE_MINUS_DECAYF;
    o.y = e.y * DECAYF + acc.y * ONE_MINUS_DECAYF;
    o.z = e.z * DECAYF + acc.z * ONE_MINUS_DECAYF;
    o.w = e.w * DECAYF + acc.w * ONE_MINUS_DECAYF;
    *(float4*)(out5 + (size_t)c * DIM + 4 * lane) = o;
    const float sc = s[c];
    float4 o3;
    o3.x = o.x / sc; o3.y = o.y / sc; o3.z = o.z / sc; o3.w = o.w / sc;
    *(float4*)(out3 + (size_t)c * DIM + 4 * lane) = o3;
}

// ---------------------------------------------------------------------------
extern "C" void kernel_launch(void* const* d_in, const int* in_sizes, int n_in,
                              void* d_out, int out_size, void* d_ws, size_t ws_size,
                              hipStream_t stream) {
    const float* z   = (const float*)d_in[0];
    const float* emb = (const float*)d_in[1];
    const float* ecs = (const float*)d_in[2];
    const float* eem = (const float*)d_in[3];

    float* out = (float*)d_out;
    float* out0 = out;                   // z_q_st         [8388608]
    float* out1 = out + 8388608;         // indices        [32768]
    float* out2 = out + 8421376;         // vq_loss        [1]
    float* out3 = out + 8421377;         // new_embedding  [2097152]
    float* out4 = out + 10518529;        // new_ema_cs     [8192]
    float* out5 = out + 10526721;        // new_ema_emb    [2097152]

    char* ws = (char*)d_ws;
    double* wPart = (double*)(ws + WS_PART);
    float*  wA    = (float*)(ws + WS_A);
    float*  wEn   = (float*)(ws + WS_EN);
    int*    wCnt  = (int*)(ws + WS_CNT);
    float*  wS    = (float*)(ws + WS_S);
    int*    wIdx  = (int*)(ws + WS_IDX);
    int*    wOffs = (int*)(ws + WS_OFFS);
    int*    wCur  = (int*)(ws + WS_CUR);
    int*    wPl   = (int*)(ws + WS_PLIST);
    float*  wGmin = (float*)(ws + WS_GMIN);
    unsigned short* wAh = (unsigned short*)(ws + WS_AH);
    unsigned short* wBh = (unsigned short*)(ws + WS_BH);

    hipLaunchKernelGGL(k_prep, dim3(NPTS / 4 + NCODES / 4), dim3(256), 0, stream,
                       z, emb, wA, wAh, wEn, wBh, wCnt);
    hipLaunchKernelGGL(k_gemm_argmin, dim3((NPTS / 128) * (NCODES / 128)), dim3(256), 0, stream,
                       wAh, wBh, wEn, wGmin);
    hipLaunchKernelGGL(k_phase2, dim3(NPTS / 4), dim3(256), 0, stream,
                       z, emb, wA, wEn, wGmin, wIdx, out1, wCnt, out0, wPart);
    hipLaunchKernelGGL(k_scan, dim3(1), dim3(256), 0, stream,
                       wCnt, ecs, wOffs, wCur, out4, wS, wPart, out2);
    hipLaunchKernelGGL(k_place, dim3(NPTS / 256), dim3(256), 0, stream, wIdx, wCur, wPl);
    hipLaunchKernelGGL(k_dw, dim3(NCODES / 4), dim3(256), 0, stream,
                       z, eem, wOffs, wCnt, wPl, wS, out5, out3);
}